// Round 11
// baseline (245.748 us; speedup 1.0000x reference)
//
#include <hip/hip_runtime.h>
#include <hip/hip_bf16.h>
#include <math.h>

#define TT 3
#define HH 96
#define WWD 96
#define CCH 128
#define HW (HH*WWD)
#define NROWS (TT*HH*WWD)   // 27648

#define ATX 4
#define ATY 2
#define AHX 8
#define AHY 6
#define NSLOT 48
#define KSTR 136

typedef __attribute__((ext_vector_type(8))) short short8;
typedef __attribute__((ext_vector_type(4))) float float4v;
typedef __attribute__((ext_vector_type(2))) float f32x2;

#if defined(__has_builtin)
#if __has_builtin(__builtin_amdgcn_fdot2_f32_bf16)
#define USE_DOT2 1
typedef __attribute__((ext_vector_type(2))) __bf16 bf2;
#endif
#endif

__device__ __forceinline__ float bfu(unsigned short u){ union{unsigned u;float f;}c; c.u=((unsigned)u)<<16; return c.f; }
__device__ __forceinline__ float bflo(unsigned u){ union{unsigned u;float f;}c; c.u=u<<16; return c.f; }
__device__ __forceinline__ float bfhi(unsigned u){ union{unsigned u;float f;}c; c.u=u&0xffff0000u; return c.f; }
__device__ __forceinline__ unsigned short f2bf(float f){ __hip_bfloat16 h=__float2bfloat16(f); return *(unsigned short*)&h; }
__device__ __forceinline__ uint4 pack8(float4 a, float4 b){
    uint4 u;
    u.x = (unsigned)f2bf(a.x) | ((unsigned)f2bf(a.y) << 16);
    u.y = (unsigned)f2bf(a.z) | ((unsigned)f2bf(a.w) << 16);
    u.z = (unsigned)f2bf(b.x) | ((unsigned)f2bf(b.y) << 16);
    u.w = (unsigned)f2bf(b.z) | ((unsigned)f2bf(b.w) << 16);
    return u;
}

// ---------------- Kernel 0: weight prep, LDS-tile transpose ----------------
__launch_bounds__(256)
__global__ void prep_kernel(const float* __restrict__ Wq, const float* __restrict__ Wk,
                            const float* __restrict__ Wv, const float* __restrict__ Wo,
                            unsigned short* __restrict__ Wt, unsigned short* __restrict__ Wo1,
                            unsigned short* __restrict__ Wo2) {
    __shared__ float ts[32][33];
    const int m = blockIdx.x >> 4, tile = blockIdx.x & 15;
    const int k0 = (tile >> 2) * 32, n0 = (tile & 3) * 32;
    const float* src = (m == 0) ? Wq : (m == 1) ? Wk : (m == 2) ? Wv : Wo;
    const int tid = threadIdx.x;
    const int c = tid & 31, r8 = tid >> 5;
#pragma unroll
    for (int rr = 0; rr < 4; ++rr) {
        int r = r8 * 4 + rr;
        ts[r][c] = src[(size_t)(k0 + r) * 128 + n0 + c];
    }
    __syncthreads();
#pragma unroll
    for (int rr = 0; rr < 4; ++rr) {
        int r = r8 * 4 + rr;
        float v = ts[c][r];
        if (m < 3) {
            Wt[(size_t)(m * 128 + n0 + r) * 128 + k0 + c] = f2bf(v);
        } else {
            unsigned short w1 = f2bf(v);
            Wo1[(size_t)(n0 + r) * 128 + k0 + c] = w1;
            Wo2[(size_t)(n0 + r) * 128 + k0 + c] = f2bf(v - bfu(w1));
        }
    }
}

// ---------------- Fused kernel: QKV-proj (MFMA) + attention (R9 core) + out-proj ----------------
// Block = 4x2 spatial tile x 3 frames; 384 thr = 6 waves.
// LDS regions (39168 B total, 4 blocks/CU):
//   Ks [0,13056)  Vs [13056,26112)  xh [26112,39168)
//   Qs alias Vs (dead until t-loop)  mb alias [0,13824) (Ks+Vs dead at merge)
//   Os alias [13824,22528) (Vs region, dead after attention)
__launch_bounds__(384)
__global__ void fused_kernel(const float* __restrict__ x,
                             const unsigned short* __restrict__ Wt,
                             const unsigned short* __restrict__ Wo1,
                             const unsigned short* __restrict__ Wo2,
                             const float* __restrict__ temp_emb,
                             const float* __restrict__ sp_emb,
                             float* __restrict__ out) {
    __shared__ __align__(16) unsigned char smem[39168];
    unsigned short* Ks = (unsigned short*)smem;
    unsigned short* Vs = (unsigned short*)(smem + 13056);
    unsigned short* xh = (unsigned short*)(smem + 26112);
    unsigned short* Qs = (unsigned short*)(smem + 13056);
    float* mb          = (float*)smem;
    unsigned short* Os = (unsigned short*)(smem + 13824);

    const int tid = threadIdx.x;
    const int lane = tid & 63;
    const int h = lane & 7, qy = (lane >> 3) & 1, qx = (lane >> 4) & 3;
    const int w = tid >> 6;
    const int tq = w % 3, s = w / 3;
    const int quad = lane >> 4, l16 = lane & 15;
    const int h16 = h * 16;

    const int bx = blockIdx.x % (WWD / ATX);
    const int by = blockIdx.x / (WWD / ATX);
    const int x0 = bx * ATX, y0 = by * ATY;
    const int xlo = min(min(max(x0, 2), 93) - 2, WWD - AHX);
    const int ylo = min(min(max(y0, 2), 93) - 2, HH - AHY);

    // ---- Phase A: Q projection for the 24 central query rows ----
    {   // stage x central rows -> xh (24 rows x 128 bf16); 384 units exactly
        int r = tid >> 4, cu = tid & 15;
        int f = r >> 3, ry = (r >> 2) & 1, rx = r & 3;
        const float* px = x + ((size_t)f * HW + (size_t)(y0 + ry) * WWD + (x0 + rx)) * CCH + cu * 8;
        float4 a = *(const float4*)px;
        float4 b = *(const float4*)(px + 4);
        *(uint4*)&xh[r * KSTR + cu * 8] = pack8(a, b);
    }
    __syncthreads();
    for (int tl = w; tl < 16; tl += 6) {
        int mtile = tl & 7, ntile = tl >> 3;
        float4v acc = (float4v){0, 0, 0, 0};
#pragma unroll
        for (int ks = 0; ks < 4; ++ks) {
            short8 a = *(const short8*)(Wt + (size_t)(mtile * 16 + l16) * CCH + ks * 32 + quad * 8);
            short8 b = *(const short8*)&xh[(ntile * 16 + l16) * KSTR + ks * 32 + quad * 8];
            acc = __builtin_amdgcn_mfma_f32_16x16x32_bf16(a, b, acc, 0, 0, 0);
        }
        int q = ntile * 16 + l16;
        if (q < 24) {
            int f = q >> 3, yy = y0 + ((q >> 2) & 1), xx = x0 + (q & 3);
            int qidx = (yy - min(max(yy, 2), 93) + 2) * 5 + (xx - min(max(xx, 2), 93) + 2);
            int ch0 = mtile * 16 + quad * 4;
            float4 te = *(const float4*)(temp_emb + f * CCH + ch0);
            float4 se = *(const float4*)(sp_emb + qidx * CCH + ch0);
            ushort4 u;
            u.x = f2bf((acc[0] + te.x + se.x) * 0.25f);
            u.y = f2bf((acc[1] + te.y + se.y) * 0.25f);
            u.z = f2bf((acc[2] + te.z + se.z) * 0.25f);
            u.w = f2bf((acc[3] + te.w + se.w) * 0.25f);
            *(ushort4*)&Qs[q * KSTR + ch0] = u;
        }
    }
    __syncthreads();

    // ---- per-thread Q state (R9) ----
    const int myq = tq * 8 + qy * 4 + qx;
    const int yy = y0 + qy, xx = x0 + qx;
    const int yc = min(max(yy, 2), 93), xc = min(max(xx, 2), 93);
    const int lyo = yc - 2 - ylo, lxo = xc - 2 - xlo;

    uint4 qa = *(const uint4*)&Qs[myq * KSTR + h16];
    uint4 qb = *(const uint4*)&Qs[myq * KSTR + h16 + 8];
    float qv[16];
    {
        const unsigned short* pa = (const unsigned short*)&qa;
        const unsigned short* pb = (const unsigned short*)&qb;
#pragma unroll
        for (int j = 0; j < 8; ++j) { qv[j] = bfu(pa[j]); qv[8 + j] = bfu(pb[j]); }
    }

    int kbase[13];
#pragma unroll
    for (int idx = 0; idx < 13; ++idx) {
        int kk = s + 2 * idx;
        int kc = (kk < 25) ? kk : 24;
        int py = (kc * 205) >> 10, px = kc - py * 5;
        kbase[idx] = ((lxo + px) * 6 + (lyo + py)) * KSTR + h16;
    }

    float qsp[13];
#pragma unroll
    for (int idx = 0; idx < 13; ++idx) {
        int kk = s + 2 * idx;
        int kc = (kk < 25) ? kk : 24;
        const float4* sp = (const float4*)(sp_emb + kc * CCH + h16);
        float a0 = 0.f;
#pragma unroll
        for (int d4 = 0; d4 < 4; ++d4) {
            float4 f = sp[d4];
            a0 += qv[d4 * 4 + 0] * f.x + qv[d4 * 4 + 1] * f.y
                + qv[d4 * 4 + 2] * f.z + qv[d4 * 4 + 3] * f.w;
        }
        qsp[idx] = (kk < 25) ? a0 : -1e30f;
    }

#ifdef USE_DOT2
    bf2 qp2[8];
    {
        const bf2* pa = (const bf2*)&qa;
        const bf2* pb = (const bf2*)&qb;
#pragma unroll
        for (int j = 0; j < 4; ++j) { qp2[j] = pa[j]; qp2[4 + j] = pb[j]; }
    }
#endif

    float m = -1e30f, l = 0.f;
    f32x2 acc2[8];
#pragma unroll
    for (int d = 0; d < 8; ++d) acc2[d] = (f32x2){0.f, 0.f};

    // ---- Phase B: per-frame K/V projection + attention core ----
    for (int t = 0; t < TT; ++t) {
        __syncthreads();
        for (int e = tid; e < NSLOT * 16; e += 384) {
            int slot = e >> 4, cu = e & 15;
            int gy = ylo + slot % 6, gx = xlo + slot / 6;
            const float* px = x + ((size_t)t * HW + (size_t)gy * WWD + gx) * CCH + cu * 8;
            float4 a = *(const float4*)px;
            float4 b = *(const float4*)(px + 4);
            *(uint4*)&xh[slot * KSTR + cu * 8] = pack8(a, b);
        }
        __syncthreads();
        {   // K/V MFMA: wave w -> mat = w&1 (0=K,1=V), p = w>>1 covers 8 (mtile,ntile)
            int mat = w & 1, p = w >> 1;
#pragma unroll
            for (int i = 0; i < 8; ++i) {
                int c = p + 3 * i;
                int mtile = c & 7, ntile = c >> 3;
                float4v acc = (float4v){0, 0, 0, 0};
#pragma unroll
                for (int ks = 0; ks < 4; ++ks) {
                    short8 a = *(const short8*)(Wt + (size_t)((1 + mat) * 128 + mtile * 16 + l16) * CCH + ks * 32 + quad * 8);
                    short8 b = *(const short8*)&xh[(ntile * 16 + l16) * KSTR + ks * 32 + quad * 8];
                    acc = __builtin_amdgcn_mfma_f32_16x16x32_bf16(a, b, acc, 0, 0, 0);
                }
                int slot = ntile * 16 + l16;
                int ch0 = mtile * 16 + quad * 4;
                ushort4 u;
                if (mat == 0) {
                    float4 te = *(const float4*)(temp_emb + t * CCH + ch0);
                    u.x = f2bf(acc[0] + te.x); u.y = f2bf(acc[1] + te.y);
                    u.z = f2bf(acc[2] + te.z); u.w = f2bf(acc[3] + te.w);
                    *(ushort4*)&Ks[slot * KSTR + ch0] = u;
                } else {
                    u.x = f2bf(acc[0]); u.y = f2bf(acc[1]);
                    u.z = f2bf(acc[2]); u.w = f2bf(acc[3]);
                    *(ushort4*)&Vs[slot * KSTR + ch0] = u;
                }
            }
        }
        __syncthreads();

        // attention core (R9 verbatim)
        float sc[13];
#pragma unroll
        for (int b = 0; b < 13; b += 4) {
            uint4 ka[4], kb4[4];
#pragma unroll
            for (int j = 0; j < 4; ++j) {
                if (b + j < 13) {
                    ka[j]  = *(const uint4*)&Ks[kbase[b + j]];
                    kb4[j] = *(const uint4*)&Ks[kbase[b + j] + 8];
                }
            }
#pragma unroll
            for (int j = 0; j < 4; ++j) {
                if (b + j < 13) {
#ifdef USE_DOT2
                    const bf2* c0 = (const bf2*)&ka[j];
                    const bf2* c1 = (const bf2*)&kb4[j];
                    float t0 = qsp[b + j], t1 = 0.f;
#pragma unroll
                    for (int jj = 0; jj < 4; ++jj) {
                        t0 = __builtin_amdgcn_fdot2_f32_bf16(qp2[jj],     c0[jj], t0, false);
                        t1 = __builtin_amdgcn_fdot2_f32_bf16(qp2[4 + jj], c1[jj], t1, false);
                    }
                    sc[b + j] = t0 + t1;
#else
                    const unsigned short* p0 = (const unsigned short*)&ka[j];
                    const unsigned short* p1 = (const unsigned short*)&kb4[j];
                    float a0 = 0.f, a1 = 0.f;
#pragma unroll
                    for (int jj = 0; jj < 8; ++jj) {
                        a0 += qv[jj] * bfu(p0[jj]);
                        a1 += qv[8 + jj] * bfu(p1[jj]);
                    }
                    sc[b + j] = a0 + a1 + qsp[b + j];
#endif
                }
            }
        }

        float fm = m;
#pragma unroll
        for (int idx = 0; idx < 13; ++idx) fm = fmaxf(fm, sc[idx]);
        float corr = __expf(m - fm);
        m = fm; l *= corr;
        f32x2 corr2 = (f32x2){corr, corr};
#pragma unroll
        for (int d = 0; d < 8; ++d) acc2[d] *= corr2;

#pragma unroll
        for (int b = 0; b < 13; b += 4) {
            uint4 va[4], vb4[4];
#pragma unroll
            for (int j = 0; j < 4; ++j) {
                if (b + j < 13) {
                    va[j]  = *(const uint4*)&Vs[kbase[b + j]];
                    vb4[j] = *(const uint4*)&Vs[kbase[b + j] + 8];
                }
            }
#pragma unroll
            for (int j = 0; j < 4; ++j) {
                if (b + j < 13) {
                    float wv = __expf(sc[b + j] - m);
                    l += wv;
                    f32x2 wv2 = (f32x2){wv, wv};
                    const unsigned* u0 = (const unsigned*)&va[j];
                    const unsigned* u1 = (const unsigned*)&vb4[j];
#pragma unroll
                    for (int jj = 0; jj < 4; ++jj) {
                        f32x2 v0; v0.x = bflo(u0[jj]); v0.y = bfhi(u0[jj]);
                        f32x2 v1; v1.x = bflo(u1[jj]); v1.y = bfhi(u1[jj]);
                        acc2[jj]     += wv2 * v0;
                        acc2[4 + jj] += wv2 * v1;
                    }
                }
            }
        }
    }

    // ---- Phase C: merge key-split halves -> Os (LDS), then out-projection ----
    __syncthreads();
    int pair = tq * 64 + lane;
    const float* accf = (const float*)acc2;
    if (s == 1) {
        float* p = mb + pair * 18;
#pragma unroll
        for (int d = 0; d < 16; ++d) p[d] = accf[d];
        p[16] = m; p[17] = l;
    }
    __syncthreads();
    if (s == 0) {
        const float* p = mb + pair * 18;
        float m1 = p[16], l1 = p[17];
        float M = fmaxf(m, m1);
        float c0 = __expf(m - M), c1 = __expf(m1 - M);
        float inv = 1.f / (l * c0 + l1 * c1);
        unsigned short ob[16];
#pragma unroll
        for (int d = 0; d < 16; ++d)
            ob[d] = f2bf((accf[d] * c0 + p[d] * c1) * inv);
        *(uint4*)&Os[myq * KSTR + h16]     = *(uint4*)&ob[0];
        *(uint4*)&Os[myq * KSTR + h16 + 8] = *(uint4*)&ob[8];
    }
    __syncthreads();

    for (int tl = w; tl < 16; tl += 6) {
        int mtile = tl & 7, ntile = tl >> 3;
        float4v acc = (float4v){0, 0, 0, 0};
#pragma unroll
        for (int ks = 0; ks < 4; ++ks) {
            size_t wo = (size_t)(mtile * 16 + l16) * CCH + ks * 32 + quad * 8;
            short8 a1 = *(const short8*)(Wo1 + wo);
            short8 a2 = *(const short8*)(Wo2 + wo);
            short8 b = *(const short8*)&Os[(ntile * 16 + l16) * KSTR + ks * 32 + quad * 8];
            acc = __builtin_amdgcn_mfma_f32_16x16x32_bf16(a1, b, acc, 0, 0, 0);
            acc = __builtin_amdgcn_mfma_f32_16x16x32_bf16(a2, b, acc, 0, 0, 0);
        }
        int q = ntile * 16 + l16;
        if (q < 24) {
            int f = q >> 3, oy = y0 + ((q >> 2) & 1), ox = x0 + (q & 3);
            float4 o;
            o.x = acc[0]; o.y = acc[1]; o.z = acc[2]; o.w = acc[3];
            *(float4*)(out + ((size_t)(oy * WWD + ox) * TT + f) * CCH + mtile * 16 + quad * 4) = o;
        }
    }
}

extern "C" void kernel_launch(void* const* d_in, const int* in_sizes, int n_in,
                              void* d_out, int out_size, void* d_ws, size_t ws_size,
                              hipStream_t stream) {
    const float* x        = (const float*)d_in[0];
    const float* Wq       = (const float*)d_in[1];
    const float* Wk       = (const float*)d_in[2];
    const float* Wv       = (const float*)d_in[3];
    const float* Wo       = (const float*)d_in[4];
    const float* temp_emb = (const float*)d_in[5];
    const float* sp_emb   = (const float*)d_in[6];
    float* out = (float*)d_out;

    unsigned short* Wt  = (unsigned short*)d_ws;           // 384x128 bf16
    unsigned short* Wo1 = Wt + 384 * 128;                  // 128x128
    unsigned short* Wo2 = Wo1 + 128 * 128;                 // 128x128

    prep_kernel<<<64, 256, 0, stream>>>(Wq, Wk, Wv, Wo, Wt, Wo1, Wo2);
    fused_kernel<<<(HH / ATY) * (WWD / ATX), 384, 0, stream>>>(
        x, Wt, Wo1, Wo2, temp_emb, sp_emb, out);
}

// Round 12
// 207.820 us; speedup vs baseline: 1.1825x; 1.1825x over previous
//
#include <hip/hip_runtime.h>
#include <hip/hip_bf16.h>
#include <math.h>

#define TT 3
#define HH 96
#define WWD 96
#define CCH 128
#define HW (HH*WWD)
#define NROWS (TT*HH*WWD)   // 27648

typedef __attribute__((ext_vector_type(8))) short short8;
typedef __attribute__((ext_vector_type(4))) float float4v;
typedef __attribute__((ext_vector_type(2))) float f32x2;

#if defined(__has_builtin)
#if __has_builtin(__builtin_amdgcn_fdot2_f32_bf16)
#define USE_DOT2 1
typedef __attribute__((ext_vector_type(2))) __bf16 bf2;
#endif
#endif

__device__ __forceinline__ float bfu(unsigned short u){ union{unsigned u;float f;}c; c.u=((unsigned)u)<<16; return c.f; }
__device__ __forceinline__ float bflo(unsigned u){ union{unsigned u;float f;}c; c.u=u<<16; return c.f; }
__device__ __forceinline__ float bfhi(unsigned u){ union{unsigned u;float f;}c; c.u=u&0xffff0000u; return c.f; }
__device__ __forceinline__ unsigned short f2bf(float f){ __hip_bfloat16 h=__float2bfloat16(f); return *(unsigned short*)&h; }

// ---------------- Kernel 0: weight prep, LDS-tile transpose ----------------
__launch_bounds__(256)
__global__ void prep_kernel(const float* __restrict__ Wq, const float* __restrict__ Wk,
                            const float* __restrict__ Wv, const float* __restrict__ Wo,
                            unsigned short* __restrict__ Wt, unsigned short* __restrict__ Wo1,
                            unsigned short* __restrict__ Wo2) {
    __shared__ float ts[32][33];
    const int m = blockIdx.x >> 4, tile = blockIdx.x & 15;
    const int k0 = (tile >> 2) * 32, n0 = (tile & 3) * 32;
    const float* src = (m == 0) ? Wq : (m == 1) ? Wk : (m == 2) ? Wv : Wo;
    const int tid = threadIdx.x;
    const int c = tid & 31, r8 = tid >> 5;
#pragma unroll
    for (int rr = 0; rr < 4; ++rr) {
        int r = r8 * 4 + rr;
        ts[r][c] = src[(size_t)(k0 + r) * 128 + n0 + c];
    }
    __syncthreads();
#pragma unroll
    for (int rr = 0; rr < 4; ++rr) {
        int r = r8 * 4 + rr;
        float v = ts[c][r];
        if (m < 3) {
            Wt[(size_t)(m * 128 + n0 + r) * 128 + k0 + c] = f2bf(v);
        } else {
            unsigned short w1 = f2bf(v);
            Wo1[(size_t)(n0 + r) * 128 + k0 + c] = w1;
            Wo2[(size_t)(n0 + r) * 128 + k0 + c] = f2bf(v - bfu(w1));
        }
    }
}

// ---------------- Kernel 1: QKV projection, bf16 MFMA, M32 x N192 split (R10) ----------------
__launch_bounds__(256)
__global__ void qkv_kernel(const float* __restrict__ x,
                           const unsigned short* __restrict__ Wt,
                           const float* __restrict__ temp_emb,
                           const float* __restrict__ sp_emb,
                           unsigned short* __restrict__ Qb,
                           unsigned short* __restrict__ Kb,
                           unsigned short* __restrict__ Vb) {
    __shared__ unsigned short xs[32 * 136];
    const int tid = threadIdx.x;
    const int q0 = (blockIdx.x >> 1) * 32;
    const int half = blockIdx.x & 1;
    for (int e = tid; e < 1024; e += 256) {
        int row = e >> 5, col = (e & 31) * 4;
        float4 v = *(const float4*)(x + (size_t)(q0 + row) * CCH + col);
        ushort4 u; u.x = f2bf(v.x); u.y = f2bf(v.y); u.z = f2bf(v.z); u.w = f2bf(v.w);
        *(ushort4*)&xs[row * 136 + col] = u;
    }
    __syncthreads();
    const int w = tid >> 6, lane = tid & 63, quad = lane >> 4, l16 = lane & 15;
    const int c0 = half * 192 + w * 48;
    float4v acc[3][2];
#pragma unroll
    for (int mt = 0; mt < 3; ++mt) { acc[mt][0] = (float4v){0,0,0,0}; acc[mt][1] = (float4v){0,0,0,0}; }
#pragma unroll
    for (int ks = 0; ks < 4; ++ks) {
        short8 b0 = *(const short8*)&xs[l16 * 136 + ks * 32 + quad * 8];
        short8 b1 = *(const short8*)&xs[(16 + l16) * 136 + ks * 32 + quad * 8];
#pragma unroll
        for (int mt = 0; mt < 3; ++mt) {
            short8 a = *(const short8*)(Wt + (size_t)(c0 + mt * 16 + l16) * CCH + ks * 32 + quad * 8);
            acc[mt][0] = __builtin_amdgcn_mfma_f32_16x16x32_bf16(a, b0, acc[mt][0], 0, 0, 0);
            acc[mt][1] = __builtin_amdgcn_mfma_f32_16x16x32_bf16(a, b1, acc[mt][1], 0, 0, 0);
        }
    }
#pragma unroll
    for (int nt = 0; nt < 2; ++nt) {
        int q = q0 + nt * 16 + l16;
        int t = q / (HH * WWD); int rem = q - t * (HH * WWD);
        int yy = rem / WWD, xx = rem - (rem / WWD) * WWD;
        int qidx = (yy - min(max(yy, 2), 93) + 2) * 5 + (xx - min(max(xx, 2), 93) + 2);
#pragma unroll
        for (int mt = 0; mt < 3; ++mt) {
            int colc = c0 + mt * 16 + quad * 4;
            int mat = colc >> 7, colb = colc & 127;
            float4v a = acc[mt][nt];
            ushort4 u;
            if (mat == 0) {
                float4 te = *(const float4*)(temp_emb + t * CCH + colb);
                float4 se = *(const float4*)(sp_emb + qidx * CCH + colb);
                u.x = f2bf((a[0] + te.x + se.x) * 0.25f);
                u.y = f2bf((a[1] + te.y + se.y) * 0.25f);
                u.z = f2bf((a[2] + te.z + se.z) * 0.25f);
                u.w = f2bf((a[3] + te.w + se.w) * 0.25f);
                *(ushort4*)(Qb + (size_t)q * CCH + colb) = u;
            } else if (mat == 1) {
                float4 te = *(const float4*)(temp_emb + t * CCH + colb);
                u.x = f2bf(a[0] + te.x); u.y = f2bf(a[1] + te.y);
                u.z = f2bf(a[2] + te.z); u.w = f2bf(a[3] + te.w);
                *(ushort4*)(Kb + (size_t)q * CCH + colb) = u;
            } else {
                u.x = f2bf(a[0]); u.y = f2bf(a[1]); u.z = f2bf(a[2]); u.w = f2bf(a[3]);
                *(ushort4*)(Vb + (size_t)q * CCH + colb) = u;
            }
        }
    }
}

// ---------------- Kernel 2: attention, double-buffered LDS + register prefetch ----------------
// R12: per frame = [ds_write prefetched regs -> buf^1 || compute buf^0] -> barrier.
// Barriers 8 -> 4; global staging latency hidden one frame ahead. Merge buffer
// aliases buf1 (dead during frame 2). Core math identical to R9/R10.
#define ATX 4
#define ATY 2
#define AHX 8
#define AHY 6
#define NSLOT 48
#define KSTR 136
#define KVHALF (NSLOT * KSTR)          // shorts per K (or V) plane = 6528

__launch_bounds__(384)
__global__ void attn_kernel(const unsigned short* Qb,
                            const unsigned short* __restrict__ Kb,
                            const unsigned short* __restrict__ Vb,
                            const float* __restrict__ sp_emb,
                            unsigned short* Ob) {
    __shared__ __align__(16) unsigned short KV[4 * KVHALF];   // 52224 B: buf0{K,V}, buf1{K,V}
    float* mb = (float*)(KV + 2 * KVHALF);                    // aliases buf1 (13824 B <= 26112)

    const int tid = threadIdx.x;
    const int lane = tid & 63;
    const int h = lane & 7, qy = (lane >> 3) & 1, qx = (lane >> 4) & 3;
    const int w = tid >> 6;
    const int tq = w % 3, s = w / 3;

    const int bx = blockIdx.x % (WWD / ATX);
    const int by = blockIdx.x / (WWD / ATX);
    const int x0 = bx * ATX, y0 = by * ATY;
    const int xlo = min(min(max(x0, 2), 93) - 2, WWD - AHX);
    const int ylo = min(min(max(y0, 2), 93) - 2, HH - AHY);
    const int yy = y0 + qy, xx = x0 + qx;
    const int yc = min(max(yy, 2), 93), xc = min(max(xx, 2), 93);
    const int lyo = yc - 2 - ylo, lxo = xc - 2 - xlo;
    const int h16 = h * 16;
    const int qrow = tq * HW + yy * WWD + xx;

    // staging geometry: this thread owns 2 (slot,chunk) units per frame
    int loff[2];
    size_t goff[2];
#pragma unroll
    for (int j = 0; j < 2; ++j) {
        int e = tid + j * 384;
        int slot = e >> 4, c = e & 15;
        int gy = ylo + slot % 6, gx = xlo + slot / 6;
        loff[j] = slot * KSTR + c * 8;
        goff[j] = ((size_t)gy * WWD + gx) * CCH + c * 8;
    }

    uint4 qa = *(const uint4*)(Qb + (size_t)qrow * CCH + h16);
    uint4 qb = *(const uint4*)(Qb + (size_t)qrow * CCH + h16 + 8);
    float qv[16];
    {
        const unsigned short* pa = (const unsigned short*)&qa;
        const unsigned short* pb = (const unsigned short*)&qb;
#pragma unroll
        for (int j = 0; j < 8; ++j) { qv[j] = bfu(pa[j]); qv[8 + j] = bfu(pb[j]); }
    }

    int kbase[13];
#pragma unroll
    for (int idx = 0; idx < 13; ++idx) {
        int kk = s + 2 * idx;
        int kc = (kk < 25) ? kk : 24;
        int py = (kc * 205) >> 10, px = kc - py * 5;
        kbase[idx] = ((lxo + px) * 6 + (lyo + py)) * KSTR + h16;
    }

    float qsp[13];
#pragma unroll
    for (int idx = 0; idx < 13; ++idx) {
        int kk = s + 2 * idx;
        int kc = (kk < 25) ? kk : 24;
        const float4* sp = (const float4*)(sp_emb + kc * CCH + h16);
        float a0 = 0.f;
#pragma unroll
        for (int d4 = 0; d4 < 4; ++d4) {
            float4 f = sp[d4];
            a0 += qv[d4 * 4 + 0] * f.x + qv[d4 * 4 + 1] * f.y
                + qv[d4 * 4 + 2] * f.z + qv[d4 * 4 + 3] * f.w;
        }
        qsp[idx] = (kk < 25) ? a0 : -1e30f;
    }

#ifdef USE_DOT2
    bf2 qp2[8];
    {
        const bf2* pa = (const bf2*)&qa;
        const bf2* pb = (const bf2*)&qb;
#pragma unroll
        for (int j = 0; j < 4; ++j) { qp2[j] = pa[j]; qp2[4 + j] = pb[j]; }
    }
#endif

    float m = -1e30f, l = 0.f;
    f32x2 acc2[8];
#pragma unroll
    for (int d = 0; d < 8; ++d) acc2[d] = (f32x2){0.f, 0.f};

    // prologue: prefetch f0 -> write buf0 -> prefetch f1 -> barrier
    uint4 kpre[2], vpre[2];
#pragma unroll
    for (int j = 0; j < 2; ++j) {
        kpre[j] = *(const uint4*)(Kb + goff[j]);
        vpre[j] = *(const uint4*)(Vb + goff[j]);
    }
    {
        unsigned short* Ksb = KV;
        unsigned short* Vsb = KV + KVHALF;
#pragma unroll
        for (int j = 0; j < 2; ++j) {
            *(uint4*)&Ksb[loff[j]] = kpre[j];
            *(uint4*)&Vsb[loff[j]] = vpre[j];
        }
    }
#pragma unroll
    for (int j = 0; j < 2; ++j) {
        kpre[j] = *(const uint4*)(Kb + (size_t)HW * CCH + goff[j]);
        vpre[j] = *(const uint4*)(Vb + (size_t)HW * CCH + goff[j]);
    }
    __syncthreads();

    for (int t = 0; t < TT; ++t) {
        const unsigned short* Ks = KV + (t & 1) * 2 * KVHALF;
        const unsigned short* Vs = Ks + KVHALF;
        if (t < 2) {
            // write prefetched frame t+1 into the other buffer
            unsigned short* Ksn = KV + ((t + 1) & 1) * 2 * KVHALF;
            unsigned short* Vsn = Ksn + KVHALF;
#pragma unroll
            for (int j = 0; j < 2; ++j) {
                *(uint4*)&Ksn[loff[j]] = kpre[j];
                *(uint4*)&Vsn[loff[j]] = vpre[j];
            }
            if (t == 0) {   // prefetch frame 2
#pragma unroll
                for (int j = 0; j < 2; ++j) {
                    kpre[j] = *(const uint4*)(Kb + (size_t)2 * HW * CCH + goff[j]);
                    vpre[j] = *(const uint4*)(Vb + (size_t)2 * HW * CCH + goff[j]);
                }
            }
        }

        // ---- compute frame t from Ks/Vs ----
        float sc[13];
#pragma unroll
        for (int b = 0; b < 13; b += 4) {
            uint4 ka[4], kb4[4];
#pragma unroll
            for (int j = 0; j < 4; ++j) {
                if (b + j < 13) {
                    ka[j]  = *(const uint4*)&Ks[kbase[b + j]];
                    kb4[j] = *(const uint4*)&Ks[kbase[b + j] + 8];
                }
            }
#pragma unroll
            for (int j = 0; j < 4; ++j) {
                if (b + j < 13) {
#ifdef USE_DOT2
                    const bf2* c0 = (const bf2*)&ka[j];
                    const bf2* c1 = (const bf2*)&kb4[j];
                    float t0 = qsp[b + j], t1 = 0.f;
#pragma unroll
                    for (int jj = 0; jj < 4; ++jj) {
                        t0 = __builtin_amdgcn_fdot2_f32_bf16(qp2[jj],     c0[jj], t0, false);
                        t1 = __builtin_amdgcn_fdot2_f32_bf16(qp2[4 + jj], c1[jj], t1, false);
                    }
                    sc[b + j] = t0 + t1;
#else
                    const unsigned short* p0 = (const unsigned short*)&ka[j];
                    const unsigned short* p1 = (const unsigned short*)&kb4[j];
                    float a0 = 0.f, a1 = 0.f;
#pragma unroll
                    for (int jj = 0; jj < 8; ++jj) {
                        a0 += qv[jj] * bfu(p0[jj]);
                        a1 += qv[8 + jj] * bfu(p1[jj]);
                    }
                    sc[b + j] = a0 + a1 + qsp[b + j];
#endif
                }
            }
        }

        float fm = m;
#pragma unroll
        for (int idx = 0; idx < 13; ++idx) fm = fmaxf(fm, sc[idx]);
        float corr = __expf(m - fm);
        m = fm; l *= corr;
        f32x2 corr2 = (f32x2){corr, corr};
#pragma unroll
        for (int d = 0; d < 8; ++d) acc2[d] *= corr2;

#pragma unroll
        for (int b = 0; b < 13; b += 4) {
            uint4 va[4], vb4[4];
#pragma unroll
            for (int j = 0; j < 4; ++j) {
                if (b + j < 13) {
                    va[j]  = *(const uint4*)&Vs[kbase[b + j]];
                    vb4[j] = *(const uint4*)&Vs[kbase[b + j] + 8];
                }
            }
#pragma unroll
            for (int j = 0; j < 4; ++j) {
                if (b + j < 13) {
                    float wv = __expf(sc[b + j] - m);
                    l += wv;
                    f32x2 wv2 = (f32x2){wv, wv};
                    const unsigned* u0 = (const unsigned*)&va[j];
                    const unsigned* u1 = (const unsigned*)&vb4[j];
#pragma unroll
                    for (int jj = 0; jj < 4; ++jj) {
                        f32x2 v0; v0.x = bflo(u0[jj]); v0.y = bfhi(u0[jj]);
                        f32x2 v1; v1.x = bflo(u1[jj]); v1.y = bfhi(u1[jj]);
                        acc2[jj]     += wv2 * v0;
                        acc2[4 + jj] += wv2 * v1;
                    }
                }
            }
        }

        if (t < 2) __syncthreads();   // release buf^1 writes / protect next overwrite
    }

    // merge: frame-2 compute used buf0; mb aliases buf1 (dead) -> only one barrier
    int pair = tq * 64 + lane;
    const float* accf = (const float*)acc2;
    if (s == 1) {
        float* p = mb + pair * 18;
#pragma unroll
        for (int d = 0; d < 16; ++d) p[d] = accf[d];
        p[16] = m; p[17] = l;
    }
    __syncthreads();
    if (s == 0) {
        const float* p = mb + pair * 18;
        float m1 = p[16], l1 = p[17];
        float M = fmaxf(m, m1);
        float c0 = __expf(m - M), c1 = __expf(m1 - M);
        float inv = 1.f / (l * c0 + l1 * c1);
        unsigned short ob[16];
#pragma unroll
        for (int d = 0; d < 16; ++d)
            ob[d] = f2bf((accf[d] * c0 + p[d] * c1) * inv);
        *(uint4*)(Ob + (size_t)qrow * CCH + h16)     = *(uint4*)&ob[0];
        *(uint4*)(Ob + (size_t)qrow * CCH + h16 + 8) = *(uint4*)&ob[8];
    }
}

// ---------------- Kernel 3: output projection, M32 x N64 split (R10) ----------------
__launch_bounds__(256)
__global__ void out_proj_kernel(const unsigned short* __restrict__ A,
                                const unsigned short* __restrict__ Wo1,
                                const unsigned short* __restrict__ Wo2,
                                float* __restrict__ out) {
    __shared__ unsigned short as[32 * 136];
    const int tid = threadIdx.x;
    const int q0 = (blockIdx.x >> 1) * 32;
    const int half = blockIdx.x & 1;
    for (int e = tid; e < 512; e += 256) {
        int row = e >> 4, c = e & 15;
        *(uint4*)&as[row * 136 + c * 8] = *(const uint4*)(A + (size_t)(q0 + row) * CCH + c * 8);
    }
    __syncthreads();
    const int w = tid >> 6, lane = tid & 63, quad = lane >> 4, l16 = lane & 15;
    const int c0 = half * 64 + w * 16;
    float4v acc[2];
    acc[0] = (float4v){0,0,0,0}; acc[1] = (float4v){0,0,0,0};
#pragma unroll
    for (int ks = 0; ks < 4; ++ks) {
        short8 b0 = *(const short8*)&as[l16 * 136 + ks * 32 + quad * 8];
        short8 b1 = *(const short8*)&as[(16 + l16) * 136 + ks * 32 + quad * 8];
        size_t wo = (size_t)(c0 + l16) * CCH + ks * 32 + quad * 8;
        short8 a1 = *(const short8*)(Wo1 + wo);
        short8 a2 = *(const short8*)(Wo2 + wo);
        acc[0] = __builtin_amdgcn_mfma_f32_16x16x32_bf16(a1, b0, acc[0], 0, 0, 0);
        acc[0] = __builtin_amdgcn_mfma_f32_16x16x32_bf16(a2, b0, acc[0], 0, 0, 0);
        acc[1] = __builtin_amdgcn_mfma_f32_16x16x32_bf16(a1, b1, acc[1], 0, 0, 0);
        acc[1] = __builtin_amdgcn_mfma_f32_16x16x32_bf16(a2, b1, acc[1], 0, 0, 0);
    }
#pragma unroll
    for (int nt = 0; nt < 2; ++nt) {
        int q = q0 + nt * 16 + l16;
        int t = q / (HH * WWD); int rem = q - t * (HH * WWD);
        int yy = rem / WWD, xx = rem - (rem / WWD) * WWD;
        size_t ob = ((size_t)(yy * WWD + xx) * TT + t) * CCH;
        float4 o;
        o.x = acc[nt][0]; o.y = acc[nt][1];
        o.z = acc[nt][2]; o.w = acc[nt][3];
        *(float4*)(out + ob + c0 + quad * 4) = o;
    }
}

extern "C" void kernel_launch(void* const* d_in, const int* in_sizes, int n_in,
                              void* d_out, int out_size, void* d_ws, size_t ws_size,
                              hipStream_t stream) {
    const float* x        = (const float*)d_in[0];
    const float* Wq       = (const float*)d_in[1];
    const float* Wk       = (const float*)d_in[2];
    const float* Wv       = (const float*)d_in[3];
    const float* Wo       = (const float*)d_in[4];
    const float* temp_emb = (const float*)d_in[5];
    const float* sp_emb   = (const float*)d_in[6];
    float* out = (float*)d_out;

    const size_t nb = (size_t)NROWS * CCH * 2;   // bytes per bf16 buffer
    unsigned short* Qb  = (unsigned short*)d_ws;
    unsigned short* Kb  = (unsigned short*)((char*)d_ws + nb);
    unsigned short* Vb  = (unsigned short*)((char*)d_ws + 2 * nb);
    unsigned short* Wt  = (unsigned short*)((char*)d_ws + 3 * nb);
    unsigned short* Wo1 = Wt + 384 * 128;
    unsigned short* Wo2 = Wo1 + 128 * 128;

    prep_kernel<<<64, 256, 0, stream>>>(Wq, Wk, Wv, Wo, Wt, Wo1, Wo2);
    qkv_kernel<<<(NROWS / 32) * 2, 256, 0, stream>>>(x, Wt, temp_emb, sp_emb, Qb, Kb, Vb);
    attn_kernel<<<(HH / ATY) * (WWD / ATX), 384, 0, stream>>>(Qb, Kb, Vb, sp_emb, Qb);
    out_proj_kernel<<<(NROWS / 32) * 2, 256, 0, stream>>>(Qb, Wo1, Wo2, out);
}

// Round 13
// 196.405 us; speedup vs baseline: 1.2512x; 1.0581x over previous
//
#include <hip/hip_runtime.h>
#include <hip/hip_bf16.h>
#include <math.h>

#define TT 3
#define HH 96
#define WWD 96
#define CCH 128
#define HW (HH*WWD)
#define NROWS (TT*HH*WWD)   // 27648

typedef __attribute__((ext_vector_type(8))) short short8;
typedef __attribute__((ext_vector_type(4))) float float4v;
typedef __attribute__((ext_vector_type(2))) float f32x2;

#if defined(__has_builtin)
#if __has_builtin(__builtin_amdgcn_fdot2_f32_bf16)
#define USE_DOT2 1
typedef __attribute__((ext_vector_type(2))) __bf16 bf2;
#endif
#endif

__device__ __forceinline__ float bfu(unsigned short u){ union{unsigned u;float f;}c; c.u=((unsigned)u)<<16; return c.f; }
__device__ __forceinline__ float bflo(unsigned u){ union{unsigned u;float f;}c; c.u=u<<16; return c.f; }
__device__ __forceinline__ float bfhi(unsigned u){ union{unsigned u;float f;}c; c.u=u&0xffff0000u; return c.f; }
__device__ __forceinline__ unsigned short f2bf(float f){ __hip_bfloat16 h=__float2bfloat16(f); return *(unsigned short*)&h; }

// ---------------- Kernel 0: weight prep, LDS-tile transpose (R10, frozen) ----------------
__launch_bounds__(256)
__global__ void prep_kernel(const float* __restrict__ Wq, const float* __restrict__ Wk,
                            const float* __restrict__ Wv, const float* __restrict__ Wo,
                            unsigned short* __restrict__ Wt, unsigned short* __restrict__ Wo1,
                            unsigned short* __restrict__ Wo2) {
    __shared__ float ts[32][33];
    const int m = blockIdx.x >> 4, tile = blockIdx.x & 15;
    const int k0 = (tile >> 2) * 32, n0 = (tile & 3) * 32;
    const float* src = (m == 0) ? Wq : (m == 1) ? Wk : (m == 2) ? Wv : Wo;
    const int tid = threadIdx.x;
    const int c = tid & 31, r8 = tid >> 5;
#pragma unroll
    for (int rr = 0; rr < 4; ++rr) {
        int r = r8 * 4 + rr;
        ts[r][c] = src[(size_t)(k0 + r) * 128 + n0 + c];
    }
    __syncthreads();
#pragma unroll
    for (int rr = 0; rr < 4; ++rr) {
        int r = r8 * 4 + rr;
        float v = ts[c][r];
        if (m < 3) {
            Wt[(size_t)(m * 128 + n0 + r) * 128 + k0 + c] = f2bf(v);
        } else {
            unsigned short w1 = f2bf(v);
            Wo1[(size_t)(n0 + r) * 128 + k0 + c] = w1;
            Wo2[(size_t)(n0 + r) * 128 + k0 + c] = f2bf(v - bfu(w1));
        }
    }
}

// ---------------- Kernel 1: QKV projection, bf16 MFMA, M32 x N192 split (R10, frozen) ----------------
__launch_bounds__(256)
__global__ void qkv_kernel(const float* __restrict__ x,
                           const unsigned short* __restrict__ Wt,
                           const float* __restrict__ temp_emb,
                           const float* __restrict__ sp_emb,
                           unsigned short* __restrict__ Qb,
                           unsigned short* __restrict__ Kb,
                           unsigned short* __restrict__ Vb) {
    __shared__ unsigned short xs[32 * 136];
    const int tid = threadIdx.x;
    const int q0 = (blockIdx.x >> 1) * 32;
    const int half = blockIdx.x & 1;
    for (int e = tid; e < 1024; e += 256) {
        int row = e >> 5, col = (e & 31) * 4;
        float4 v = *(const float4*)(x + (size_t)(q0 + row) * CCH + col);
        ushort4 u; u.x = f2bf(v.x); u.y = f2bf(v.y); u.z = f2bf(v.z); u.w = f2bf(v.w);
        *(ushort4*)&xs[row * 136 + col] = u;
    }
    __syncthreads();
    const int w = tid >> 6, lane = tid & 63, quad = lane >> 4, l16 = lane & 15;
    const int c0 = half * 192 + w * 48;
    float4v acc[3][2];
#pragma unroll
    for (int mt = 0; mt < 3; ++mt) { acc[mt][0] = (float4v){0,0,0,0}; acc[mt][1] = (float4v){0,0,0,0}; }
#pragma unroll
    for (int ks = 0; ks < 4; ++ks) {
        short8 b0 = *(const short8*)&xs[l16 * 136 + ks * 32 + quad * 8];
        short8 b1 = *(const short8*)&xs[(16 + l16) * 136 + ks * 32 + quad * 8];
#pragma unroll
        for (int mt = 0; mt < 3; ++mt) {
            short8 a = *(const short8*)(Wt + (size_t)(c0 + mt * 16 + l16) * CCH + ks * 32 + quad * 8);
            acc[mt][0] = __builtin_amdgcn_mfma_f32_16x16x32_bf16(a, b0, acc[mt][0], 0, 0, 0);
            acc[mt][1] = __builtin_amdgcn_mfma_f32_16x16x32_bf16(a, b1, acc[mt][1], 0, 0, 0);
        }
    }
#pragma unroll
    for (int nt = 0; nt < 2; ++nt) {
        int q = q0 + nt * 16 + l16;
        int t = q / (HH * WWD); int rem = q - t * (HH * WWD);
        int yy = rem / WWD, xx = rem - (rem / WWD) * WWD;
        int qidx = (yy - min(max(yy, 2), 93) + 2) * 5 + (xx - min(max(xx, 2), 93) + 2);
#pragma unroll
        for (int mt = 0; mt < 3; ++mt) {
            int colc = c0 + mt * 16 + quad * 4;
            int mat = colc >> 7, colb = colc & 127;
            float4v a = acc[mt][nt];
            ushort4 u;
            if (mat == 0) {
                float4 te = *(const float4*)(temp_emb + t * CCH + colb);
                float4 se = *(const float4*)(sp_emb + qidx * CCH + colb);
                u.x = f2bf((a[0] + te.x + se.x) * 0.25f);
                u.y = f2bf((a[1] + te.y + se.y) * 0.25f);
                u.z = f2bf((a[2] + te.z + se.z) * 0.25f);
                u.w = f2bf((a[3] + te.w + se.w) * 0.25f);
                *(ushort4*)(Qb + (size_t)q * CCH + colb) = u;
            } else if (mat == 1) {
                float4 te = *(const float4*)(temp_emb + t * CCH + colb);
                u.x = f2bf(a[0] + te.x); u.y = f2bf(a[1] + te.y);
                u.z = f2bf(a[2] + te.z); u.w = f2bf(a[3] + te.w);
                *(ushort4*)(Kb + (size_t)q * CCH + colb) = u;
            } else {
                u.x = f2bf(a[0]); u.y = f2bf(a[1]); u.z = f2bf(a[2]); u.w = f2bf(a[3]);
                *(ushort4*)(Vb + (size_t)q * CCH + colb) = u;
            }
        }
    }
}

// ---------------- Kernel 2: attention (R9 core, frozen) + fused out-projection ----------------
// After the merge, O (24 rows x 128 bf16) goes to LDS (aliased over dead K/V),
// then 6 waves run 16 out-proj MFMA tiles and store `out` directly.
#define ATX 4
#define ATY 2
#define AHX 8
#define AHY 6
#define NSLOT 48
#define KSTR 136

__launch_bounds__(384)
__global__ void attn_kernel(const unsigned short* Qb,
                            const unsigned short* __restrict__ Kb,
                            const unsigned short* __restrict__ Vb,
                            const float* __restrict__ sp_emb,
                            const unsigned short* __restrict__ Wo1,
                            const unsigned short* __restrict__ Wo2,
                            float* __restrict__ out) {
    __shared__ __align__(16) unsigned short KV[2 * NSLOT * KSTR];   // 26112 B
    unsigned short* Ks = KV;
    unsigned short* Vs = KV + NSLOT * KSTR;
    float* mb          = (float*)KV;                                 // [0,13824)
    unsigned short* Os = (unsigned short*)((char*)KV + 13824);       // [13824,20352)

    const int tid = threadIdx.x;
    const int lane = tid & 63;
    const int h = lane & 7, qy = (lane >> 3) & 1, qx = (lane >> 4) & 3;
    const int w = tid >> 6;
    const int tq = w % 3, s = w / 3;
    const int quad = lane >> 4, l16 = lane & 15;

    const int bx = blockIdx.x % (WWD / ATX);
    const int by = blockIdx.x / (WWD / ATX);
    const int x0 = bx * ATX, y0 = by * ATY;
    const int xlo = min(min(max(x0, 2), 93) - 2, WWD - AHX);
    const int ylo = min(min(max(y0, 2), 93) - 2, HH - AHY);
    const int yy = y0 + qy, xx = x0 + qx;
    const int yc = min(max(yy, 2), 93), xc = min(max(xx, 2), 93);
    const int lyo = yc - 2 - ylo, lxo = xc - 2 - xlo;
    const int h16 = h * 16;
    const int qrow = tq * HW + yy * WWD + xx;
    const int myq = tq * 8 + qy * 4 + qx;   // O row in Os [0,24)

    uint4 qa = *(const uint4*)(Qb + (size_t)qrow * CCH + h16);
    uint4 qb = *(const uint4*)(Qb + (size_t)qrow * CCH + h16 + 8);
    float qv[16];
    {
        const unsigned short* pa = (const unsigned short*)&qa;
        const unsigned short* pb = (const unsigned short*)&qb;
#pragma unroll
        for (int j = 0; j < 8; ++j) { qv[j] = bfu(pa[j]); qv[8 + j] = bfu(pb[j]); }
    }

    int kbase[13];
#pragma unroll
    for (int idx = 0; idx < 13; ++idx) {
        int kk = s + 2 * idx;
        int kc = (kk < 25) ? kk : 24;
        int py = (kc * 205) >> 10, px = kc - py * 5;
        kbase[idx] = ((lxo + px) * 6 + (lyo + py)) * KSTR + h16;
    }

    float qsp[13];
#pragma unroll
    for (int idx = 0; idx < 13; ++idx) {
        int kk = s + 2 * idx;
        int kc = (kk < 25) ? kk : 24;
        const float4* sp = (const float4*)(sp_emb + kc * CCH + h16);
        float a0 = 0.f;
#pragma unroll
        for (int d4 = 0; d4 < 4; ++d4) {
            float4 f = sp[d4];
            a0 += qv[d4 * 4 + 0] * f.x + qv[d4 * 4 + 1] * f.y
                + qv[d4 * 4 + 2] * f.z + qv[d4 * 4 + 3] * f.w;
        }
        qsp[idx] = (kk < 25) ? a0 : -1e30f;
    }

#ifdef USE_DOT2
    bf2 qp2[8];
    {
        const bf2* pa = (const bf2*)&qa;
        const bf2* pb = (const bf2*)&qb;
#pragma unroll
        for (int j = 0; j < 4; ++j) { qp2[j] = pa[j]; qp2[4 + j] = pb[j]; }
    }
#endif

    float m = -1e30f, l = 0.f;
    f32x2 acc2[8];
#pragma unroll
    for (int d = 0; d < 8; ++d) acc2[d] = (f32x2){0.f, 0.f};

    for (int t = 0; t < TT; ++t) {
        __syncthreads();
        for (int e = tid; e < NSLOT * 16; e += 384) {
            int slot = e >> 4, c = e & 15;
            int gy = ylo + slot % 6;
            int gx = xlo + slot / 6;
            size_t g = ((size_t)(t * HH + gy) * WWD + gx) * CCH + c * 8;
            *(uint4*)&Ks[slot * KSTR + c * 8] = *(const uint4*)(Kb + g);
            *(uint4*)&Vs[slot * KSTR + c * 8] = *(const uint4*)(Vb + g);
        }
        __syncthreads();

        float sc[13];
#pragma unroll
        for (int b = 0; b < 13; b += 4) {
            uint4 ka[4], kb4[4];
#pragma unroll
            for (int j = 0; j < 4; ++j) {
                if (b + j < 13) {
                    ka[j]  = *(const uint4*)&Ks[kbase[b + j]];
                    kb4[j] = *(const uint4*)&Ks[kbase[b + j] + 8];
                }
            }
#pragma unroll
            for (int j = 0; j < 4; ++j) {
                if (b + j < 13) {
#ifdef USE_DOT2
                    const bf2* c0 = (const bf2*)&ka[j];
                    const bf2* c1 = (const bf2*)&kb4[j];
                    float t0 = qsp[b + j], t1 = 0.f;
#pragma unroll
                    for (int jj = 0; jj < 4; ++jj) {
                        t0 = __builtin_amdgcn_fdot2_f32_bf16(qp2[jj],     c0[jj], t0, false);
                        t1 = __builtin_amdgcn_fdot2_f32_bf16(qp2[4 + jj], c1[jj], t1, false);
                    }
                    sc[b + j] = t0 + t1;
#else
                    const unsigned short* p0 = (const unsigned short*)&ka[j];
                    const unsigned short* p1 = (const unsigned short*)&kb4[j];
                    float a0 = 0.f, a1 = 0.f;
#pragma unroll
                    for (int jj = 0; jj < 8; ++jj) {
                        a0 += qv[jj] * bfu(p0[jj]);
                        a1 += qv[8 + jj] * bfu(p1[jj]);
                    }
                    sc[b + j] = a0 + a1 + qsp[b + j];
#endif
                }
            }
        }

        float fm = m;
#pragma unroll
        for (int idx = 0; idx < 13; ++idx) fm = fmaxf(fm, sc[idx]);
        float corr = __expf(m - fm);
        m = fm; l *= corr;
        f32x2 corr2 = (f32x2){corr, corr};
#pragma unroll
        for (int d = 0; d < 8; ++d) acc2[d] *= corr2;

#pragma unroll
        for (int b = 0; b < 13; b += 4) {
            uint4 va[4], vb4[4];
#pragma unroll
            for (int j = 0; j < 4; ++j) {
                if (b + j < 13) {
                    va[j]  = *(const uint4*)&Vs[kbase[b + j]];
                    vb4[j] = *(const uint4*)&Vs[kbase[b + j] + 8];
                }
            }
#pragma unroll
            for (int j = 0; j < 4; ++j) {
                if (b + j < 13) {
                    float wv = __expf(sc[b + j] - m);
                    l += wv;
                    f32x2 wv2 = (f32x2){wv, wv};
                    const unsigned* u0 = (const unsigned*)&va[j];
                    const unsigned* u1 = (const unsigned*)&vb4[j];
#pragma unroll
                    for (int jj = 0; jj < 4; ++jj) {
                        f32x2 v0; v0.x = bflo(u0[jj]); v0.y = bfhi(u0[jj]);
                        f32x2 v1; v1.x = bflo(u1[jj]); v1.y = bfhi(u1[jj]);
                        acc2[jj]     += wv2 * v0;
                        acc2[4 + jj] += wv2 * v1;
                    }
                }
            }
        }
    }

    // ---- merge key-split halves -> Os (LDS) ----
    __syncthreads();
    int pair = tq * 64 + lane;
    const float* accf = (const float*)acc2;
    if (s == 1) {
        float* p = mb + pair * 18;
#pragma unroll
        for (int d = 0; d < 16; ++d) p[d] = accf[d];
        p[16] = m; p[17] = l;
    }
    __syncthreads();
    if (s == 0) {
        const float* p = mb + pair * 18;
        float m1 = p[16], l1 = p[17];
        float M = fmaxf(m, m1);
        float c0 = __expf(m - M), c1 = __expf(m1 - M);
        float inv = 1.f / (l * c0 + l1 * c1);
        unsigned short ob[16];
#pragma unroll
        for (int d = 0; d < 16; ++d)
            ob[d] = f2bf((accf[d] * c0 + p[d] * c1) * inv);
        *(uint4*)&Os[myq * KSTR + h16]     = *(uint4*)&ob[0];
        *(uint4*)&Os[myq * KSTR + h16 + 8] = *(uint4*)&ob[8];
    }
    __syncthreads();

    // ---- fused out-projection: 16 tiles over 6 waves ----
    for (int tl = w; tl < 16; tl += 6) {
        int mtile = tl & 7, ntile = tl >> 3;
        float4v acc = (float4v){0, 0, 0, 0};
#pragma unroll
        for (int ks = 0; ks < 4; ++ks) {
            size_t wo = (size_t)(mtile * 16 + l16) * CCH + ks * 32 + quad * 8;
            short8 a1 = *(const short8*)(Wo1 + wo);
            short8 a2 = *(const short8*)(Wo2 + wo);
            short8 b = *(const short8*)&Os[(ntile * 16 + l16) * KSTR + ks * 32 + quad * 8];
            acc = __builtin_amdgcn_mfma_f32_16x16x32_bf16(a1, b, acc, 0, 0, 0);
            acc = __builtin_amdgcn_mfma_f32_16x16x32_bf16(a2, b, acc, 0, 0, 0);
        }
        int q = ntile * 16 + l16;
        if (q < 24) {
            int f = q >> 3, oy = y0 + ((q >> 2) & 1), ox = x0 + (q & 3);
            float4 o;
            o.x = acc[0]; o.y = acc[1]; o.z = acc[2]; o.w = acc[3];
            *(float4*)(out + ((size_t)(oy * WWD + ox) * TT + f) * CCH + mtile * 16 + quad * 4) = o;
        }
    }
}

extern "C" void kernel_launch(void* const* d_in, const int* in_sizes, int n_in,
                              void* d_out, int out_size, void* d_ws, size_t ws_size,
                              hipStream_t stream) {
    const float* x        = (const float*)d_in[0];
    const float* Wq       = (const float*)d_in[1];
    const float* Wk       = (const float*)d_in[2];
    const float* Wv       = (const float*)d_in[3];
    const float* Wo       = (const float*)d_in[4];
    const float* temp_emb = (const float*)d_in[5];
    const float* sp_emb   = (const float*)d_in[6];
    float* out = (float*)d_out;

    const size_t nb = (size_t)NROWS * CCH * 2;   // bytes per bf16 buffer
    unsigned short* Qb  = (unsigned short*)d_ws;
    unsigned short* Kb  = (unsigned short*)((char*)d_ws + nb);
    unsigned short* Vb  = (unsigned short*)((char*)d_ws + 2 * nb);
    unsigned short* Wt  = (unsigned short*)((char*)d_ws + 3 * nb);
    unsigned short* Wo1 = Wt + 384 * 128;
    unsigned short* Wo2 = Wo1 + 128 * 128;

    prep_kernel<<<64, 256, 0, stream>>>(Wq, Wk, Wv, Wo, Wt, Wo1, Wo2);
    qkv_kernel<<<(NROWS / 32) * 2, 256, 0, stream>>>(x, Wt, temp_emb, sp_emb, Qb, Kb, Vb);
    attn_kernel<<<(HH / ATY) * (WWD / ATX), 384, 0, stream>>>(
        Qb, Kb, Vb, sp_emb, Wo1, Wo2, out);
}